// Round 13
// baseline (241.041 us; speedup 1.0000x reference)
//
#include <hip/hip_runtime.h>
#include <math.h>

// N=100000 nodes, E=6400000 edges, avg degree 64.
// out[n] = [cos(th_n), sin(th_n), w_n],  w_n = S_y / max(||S||, eps),
//   S_x = cos(th)*C + sin(th)*S,  S_y = cos(th)*S - sin(th)*C,
//   C_n = sum_{e:dst=n} cos(x[src_e]),  S_n = sum_{e:dst=n} sin(x[src_e]).
//
// Model (R1-R12): global fp atomics write through to HBM (634us, R1/R8).
// LDS-partition scan is VISIT-bound: ~0.7 cyc/edge-visit/CU invariant
// across payload (R4/R10/R11 all ~112-118us at NPART=16 = 102M visits).
// R12 proved NPART=5 (160KB dynamic LDS) hits ~152us BUT >64KB dynamic
// LDS breaks under graph capture: hipFuncSetAttribute isn't honored at
// replay -> silent clamp -> LDS OOB garbage on replays only. NEVER exceed
// the 64KB default with graph capture.
// R13: NPART=13 -> R=7693 u64 = 61.5KB dynamic LDS (<=64KB, no opt-in,
// graph-safe), 512-thr blocks, 2 blocks/CU, nslice=40 (%8==0 -> XCD-local
// slice rescan). Visits 102M->83M. 8 edges/lane (2xint4 dst + 2xint4 src
// issued together, 8 masked pu-gathers, 8 masked ds_add_u64) for 2x MLP.
// pu table (R11) keeps VALU cold. Fixed-point u64:
// addend=(1<<52)|(sin+32768)<<26|(cos+32768), scale 2^15; deg_max ~150
// => no cross-field carry (fields 26b); decode once in reduce.
// Fixed ~70us/replay harness overhead observed across all rounds.

#define EPS 1e-12f

// ---- R13 path ----
#define NP13 13
#define BLK 512

// ---- R11-class static fallback ----
#define NPART 16
#define RMAX 6250        // u64[6250] = 50KB static LDS -> 3 blocks/CU
// ----

static __device__ __forceinline__ unsigned long long pack_cs(float xv) {
    float sn, cs;
    __sincosf(xv, &sn, &cs);
    const int ci = __float2int_rn(cs * 32768.0f);   // [-32768, 32768]
    const int si = __float2int_rn(sn * 32768.0f);
    return (1ull << 52)
         | ((unsigned long long)(unsigned)(si + 32768) << 26)
         | (unsigned long long)(unsigned)(ci + 32768);
}

// ---------------- prep: packed-addend table ----------------
__global__ __launch_bounds__(256) void prep_pack_kernel(
        const float* __restrict__ x,
        unsigned long long* __restrict__ pu, int N) {
    int i = blockIdx.x * blockDim.x + threadIdx.x;
    if (i < N) pu[i] = pack_cs(x[i]);
}

// ---------------- R13 scatter: 61.5KB dynamic LDS, 8 edges/lane ----------
__global__ __launch_bounds__(BLK) void scatter13_kernel(
        const unsigned long long* __restrict__ pu,
        const int* __restrict__ esrc,
        const int* __restrict__ edst,
        unsigned long long* __restrict__ partials,   // [NP13*nslice][R]
        int E, int R, int nslice) {
    extern __shared__ unsigned long long lacc[];
    const int p = blockIdx.x / nslice;
    const int s = blockIdx.x % nslice;   // nslice%8==0 -> XCD = blk%8 = s%8
    const int pBeg = p * R;

    for (int k = threadIdx.x; k < R; k += BLK) lacc[k] = 0ull;
    __syncthreads();

    const int per = (((E + nslice - 1) / nslice) + 7) & ~7;
    const int beg = s * per;
    const int end = min(beg + per, E);
    const int end8 = beg + (max(end - beg, 0) & ~7);

    for (int i = beg + threadIdx.x * 8; i < end8; i += BLK * 8) {
        // 4 independent index vec-loads issued together
        const int4 da = *(const int4*)&edst[i];
        const int4 db = *(const int4*)&edst[i + 4];
        const int4 sa = *(const int4*)&esrc[i];
        const int4 sb = *(const int4*)&esrc[i + 4];
        const unsigned dl0 = (unsigned)(da.x - pBeg);
        const unsigned dl1 = (unsigned)(da.y - pBeg);
        const unsigned dl2 = (unsigned)(da.z - pBeg);
        const unsigned dl3 = (unsigned)(da.w - pBeg);
        const unsigned dl4 = (unsigned)(db.x - pBeg);
        const unsigned dl5 = (unsigned)(db.y - pBeg);
        const unsigned dl6 = (unsigned)(db.z - pBeg);
        const unsigned dl7 = (unsigned)(db.w - pBeg);
        const bool h0 = dl0 < (unsigned)R, h1 = dl1 < (unsigned)R;
        const bool h2 = dl2 < (unsigned)R, h3 = dl3 < (unsigned)R;
        const bool h4 = dl4 < (unsigned)R, h5 = dl5 < (unsigned)R;
        const bool h6 = dl6 < (unsigned)R, h7 = dl7 < (unsigned)R;
        // 8 masked 8B gathers from the L2-resident pu table, all issued
        // before any atomic: one drain per 512 visits
        unsigned long long v0 = 0, v1 = 0, v2 = 0, v3 = 0;
        unsigned long long v4 = 0, v5 = 0, v6 = 0, v7 = 0;
        if (h0) v0 = pu[sa.x];
        if (h1) v1 = pu[sa.y];
        if (h2) v2 = pu[sa.z];
        if (h3) v3 = pu[sa.w];
        if (h4) v4 = pu[sb.x];
        if (h5) v5 = pu[sb.y];
        if (h6) v6 = pu[sb.z];
        if (h7) v7 = pu[sb.w];
        if (h0) atomicAdd(&lacc[dl0], v0);
        if (h1) atomicAdd(&lacc[dl1], v1);
        if (h2) atomicAdd(&lacc[dl2], v2);
        if (h3) atomicAdd(&lacc[dl3], v3);
        if (h4) atomicAdd(&lacc[dl4], v4);
        if (h5) atomicAdd(&lacc[dl5], v5);
        if (h6) atomicAdd(&lacc[dl6], v6);
        if (h7) atomicAdd(&lacc[dl7], v7);
    }
    for (int i = end8 + threadIdx.x; i < end; i += BLK) {
        const unsigned dl = (unsigned)(edst[i] - pBeg);
        if (dl < (unsigned)R) atomicAdd(&lacc[dl], pu[esrc[i]]);
    }

    __syncthreads();
    unsigned long long* dst = partials + (size_t)blockIdx.x * R;
    for (int k = threadIdx.x; k < R; k += BLK) dst[k] = lacc[k];
}

// ---------------- static fallback scatter: NPART=16, 50KB ----------------
__global__ __launch_bounds__(BLK) void scatter16_kernel(
        const unsigned long long* __restrict__ pu,
        const int* __restrict__ esrc,
        const int* __restrict__ edst,
        unsigned long long* __restrict__ partials,   // [NPART*nslice][R]
        int E, int R, int nslice) {
    __shared__ unsigned long long lacc[RMAX];
    const int p = blockIdx.x / nslice;
    const int s = blockIdx.x % nslice;
    const int pBeg = p * R;

    for (int k = threadIdx.x; k < R; k += BLK) lacc[k] = 0ull;
    __syncthreads();

    const int per = (((E + nslice - 1) / nslice) + 3) & ~3;
    const int beg = s * per;
    const int end = min(beg + per, E);
    const int end4 = beg + (max(end - beg, 0) & ~3);

    for (int i = beg + threadIdx.x * 4; i < end4; i += BLK * 4) {
        const int4 d4 = *(const int4*)&edst[i];
        const int4 s4 = *(const int4*)&esrc[i];
        const unsigned dl0 = (unsigned)(d4.x - pBeg);
        const unsigned dl1 = (unsigned)(d4.y - pBeg);
        const unsigned dl2 = (unsigned)(d4.z - pBeg);
        const unsigned dl3 = (unsigned)(d4.w - pBeg);
        const bool h0 = dl0 < (unsigned)R, h1 = dl1 < (unsigned)R;
        const bool h2 = dl2 < (unsigned)R, h3 = dl3 < (unsigned)R;
        unsigned long long v0 = 0, v1 = 0, v2 = 0, v3 = 0;
        if (h0) v0 = pu[s4.x];
        if (h1) v1 = pu[s4.y];
        if (h2) v2 = pu[s4.z];
        if (h3) v3 = pu[s4.w];
        if (h0) atomicAdd(&lacc[dl0], v0);
        if (h1) atomicAdd(&lacc[dl1], v1);
        if (h2) atomicAdd(&lacc[dl2], v2);
        if (h3) atomicAdd(&lacc[dl3], v3);
    }
    for (int i = end4 + threadIdx.x; i < end; i += BLK) {
        const unsigned dl = (unsigned)(edst[i] - pBeg);
        if (dl < (unsigned)R) atomicAdd(&lacc[dl], pu[esrc[i]]);
    }

    __syncthreads();
    unsigned long long* dst = partials + (size_t)blockIdx.x * R;
    for (int k = threadIdx.x; k < R; k += BLK) dst[k] = lacc[k];
}

// ---------------- reduce partials (raw u64 sum) + epilogue ----------------
__global__ __launch_bounds__(256) void reduce_kernel(
        const float* __restrict__ theta,
        const unsigned long long* __restrict__ partials,
        float* __restrict__ out, int N, int R, int nslice) {
    const int n = blockIdx.x * blockDim.x + threadIdx.x;
    if (n >= N) return;
    const int p = n / R;
    const int j = n - p * R;
    const unsigned long long* base = partials + (size_t)p * nslice * R + j;
    unsigned long long t = 0ull;
    #pragma unroll 8
    for (int s = 0; s < nslice; ++s) t += base[(size_t)s * R];
    const long long k  = (long long)(t >> 52);
    const long long cf = (long long)(t & 0x3FFFFFFull);
    const long long sf = (long long)((t >> 26) & 0x3FFFFFFull);
    const float C  = (float)(cf - k * 32768) * (1.0f / 32768.0f);
    const float Sv = (float)(sf - k * 32768) * (1.0f / 32768.0f);
    float sn, cs;
    __sincosf(theta[n], &sn, &cs);
    const float nrm = fmaxf(sqrtf(C * C + Sv * Sv), EPS);
    out[3 * n + 0] = cs;
    out[3 * n + 1] = sn;
    out[3 * n + 2] = (cs * Sv - sn * C) / nrm;
}

// ---------------- R8 fallback: global native atomics ----------------
__global__ __launch_bounds__(256) void prep_acc_kernel(float2* __restrict__ acc, int N) {
    int i = blockIdx.x * blockDim.x + threadIdx.x;
    if (i < N) acc[i] = make_float2(0.0f, 0.0f);
}

__global__ __launch_bounds__(256) void edge_scatter_sincos_kernel(
        const int* __restrict__ esrc,
        const int* __restrict__ edst,
        const float* __restrict__ x,
        float2* __restrict__ acc, int E) {
    const int i = (blockIdx.x * 256 + threadIdx.x) * 4;
    float* accf = (float*)acc;
    for (int k = i; k < min(i + 4, E); ++k) {
        float sn, cs;
        __sincosf(x[esrc[k]], &sn, &cs);
        const int d = edst[k];
        unsafeAtomicAdd(&accf[2 * d],     cs);
        unsafeAtomicAdd(&accf[2 * d + 1], sn);
    }
}

__global__ __launch_bounds__(256) void node_kernel(
        const float* __restrict__ theta,
        const float2* __restrict__ acc,
        float* __restrict__ out, int N) {
    int n = blockIdx.x * blockDim.x + threadIdx.x;
    if (n >= N) return;
    float sn, cs;
    __sincosf(theta[n], &sn, &cs);
    const float2 a = acc[n];
    const float nrm = fmaxf(sqrtf(a.x * a.x + a.y * a.y), EPS);
    out[3 * n + 0] = cs;
    out[3 * n + 1] = sn;
    out[3 * n + 2] = (cs * a.y - sn * a.x) / nrm;
}

extern "C" void kernel_launch(void* const* d_in, const int* in_sizes, int n_in,
                              void* d_out, int out_size, void* d_ws, size_t ws_size,
                              hipStream_t stream) {
    const float* x     = (const float*)d_in[0];
    const float* theta = (const float*)d_in[1];
    const int*   esrc  = (const int*)d_in[2];
    const int*   edst  = (const int*)d_in[3];
    float*       out   = (float*)d_out;

    const int N = in_sizes[0];
    const int E = in_sizes[2];
    const size_t pu_bytes = (size_t)N * sizeof(unsigned long long);

    // ---------- R13 path: NPART=13, 61.5KB dynamic LDS (<=64KB, no opt-in) --
    {
        const int R = (N + NP13 - 1) / NP13;
        const size_t lds_bytes = (size_t)R * sizeof(unsigned long long);
        if (lds_bytes <= 65536) {
            for (int nslice : {40, 24, 16, 8}) {
                const size_t part_bytes =
                    (size_t)NP13 * nslice * R * sizeof(unsigned long long);
                if (ws_size >= part_bytes + pu_bytes) {
                    unsigned long long* partials = (unsigned long long*)d_ws;
                    unsigned long long* pu =
                        (unsigned long long*)((char*)d_ws + part_bytes);
                    prep_pack_kernel<<<(N + 255) / 256, 256, 0, stream>>>(x, pu, N);
                    scatter13_kernel<<<NP13 * nslice, BLK, lds_bytes, stream>>>(
                        pu, esrc, edst, partials, E, R, nslice);
                    reduce_kernel<<<(N + 255) / 256, 256, 0, stream>>>(
                        theta, partials, out, N, R, nslice);
                    return;
                }
            }
        }
    }

    // ---------- static fallback: NPART=16, 50KB (R11-class, ~192us) ----------
    {
        const int R = (N + NPART - 1) / NPART;
        if (R <= RMAX) {
            for (int nslice : {48, 24, 8}) {
                const size_t part_bytes =
                    (size_t)NPART * nslice * R * sizeof(unsigned long long);
                if (ws_size >= part_bytes + pu_bytes) {
                    unsigned long long* partials = (unsigned long long*)d_ws;
                    unsigned long long* pu =
                        (unsigned long long*)((char*)d_ws + part_bytes);
                    prep_pack_kernel<<<(N + 255) / 256, 256, 0, stream>>>(x, pu, N);
                    scatter16_kernel<<<NPART * nslice, BLK, 0, stream>>>(
                        pu, esrc, edst, partials, E, R, nslice);
                    reduce_kernel<<<(N + 255) / 256, 256, 0, stream>>>(
                        theta, partials, out, N, R, nslice);
                    return;
                }
            }
        }
    }

    // ---------- R8 fallback: global native atomics ----------
    float2* acc = (float2*)d_ws;   // 800KB
    prep_acc_kernel<<<(N + 255) / 256, 256, 0, stream>>>(acc, N);
    edge_scatter_sincos_kernel<<<(E + 1023) / 1024, 256, 0, stream>>>(esrc, edst, x, acc, E);
    node_kernel<<<(N + 255) / 256, 256, 0, stream>>>(theta, acc, out, N);
}

// Round 14
// 180.295 us; speedup vs baseline: 1.3369x; 1.3369x over previous
//
#include <hip/hip_runtime.h>
#include <math.h>

// N=100000 nodes, E=6400000 edges, avg degree 64.
// out[n] = [cos(th_n), sin(th_n), w_n],  w_n = S_y / max(||S||, eps),
//   S_x = cos(th)*C + sin(th)*S,  S_y = cos(th)*S - sin(th)*C,
//   C_n = sum_{e:dst=n} cos(x[src_e]),  S_n = sum_{e:dst=n} sin(x[src_e]).
//
// Model (R1-R13): global fp atomics write through to HBM (634us, R1/R8).
// LDS-partition scan is LATENCY-bound at ~0.7 cyc/edge-visit/CU with 24
// waves/CU (R4/R10/R11 ~112us at NPART=16 = 102M visits; VALU/HBM/LDS all
// idle). R12: >64KB dynamic LDS breaks graph replay (attr not honored).
// R13: 61.5KB dynamic LDS -> only 1 block/CU resident (23% occ) -> 168us
// REGRESSION; dynamic-LDS granularity killed residency. Residency >= 3
// blocks/CU requires the static 50KB config.
// R14: NPART=16 static 50KB (guaranteed 3 blk/CU = 24 waves) + 8 edges/
// lane: 4 independent int4 index loads + 8 masked pu-gathers in flight
// before the first ds_add_u64 -> 2x per-wave MLP vs R11 at identical
// occupancy. pu table keeps VALU cold. Fixed-point u64:
// addend=(1<<52)|(sin+32768)<<26|(cos+32768), scale 2^15; per-node-per-
// slice degree << 4096 => no cross-field carry; decode once in reduce.

#define EPS 1e-12f
#define NPART 16
#define RMAX 6250        // u64[6250] = 50KB static LDS -> 3 blocks/CU
#define BLK 512

static __device__ __forceinline__ unsigned long long pack_cs(float xv) {
    float sn, cs;
    __sincosf(xv, &sn, &cs);
    const int ci = __float2int_rn(cs * 32768.0f);   // [-32768, 32768]
    const int si = __float2int_rn(sn * 32768.0f);
    return (1ull << 52)
         | ((unsigned long long)(unsigned)(si + 32768) << 26)
         | (unsigned long long)(unsigned)(ci + 32768);
}

// ---------------- prep: packed-addend table ----------------
__global__ __launch_bounds__(256) void prep_pack_kernel(
        const float* __restrict__ x,
        unsigned long long* __restrict__ pu, int N) {
    int i = blockIdx.x * blockDim.x + threadIdx.x;
    if (i < N) pu[i] = pack_cs(x[i]);
}

// ---------------- scatter: static 50KB, 8 edges/lane ----------------
__global__ __launch_bounds__(BLK, 6) void scatter_kernel(
        const unsigned long long* __restrict__ pu,
        const int* __restrict__ esrc,
        const int* __restrict__ edst,
        unsigned long long* __restrict__ partials,   // [NPART*nslice][R]
        int E, int R, int nslice) {
    __shared__ unsigned long long lacc[RMAX];
    const int p = blockIdx.x / nslice;
    const int s = blockIdx.x % nslice;   // nslice%8==0 -> XCD = blk%8 = s%8
    const int pBeg = p * R;

    for (int k = threadIdx.x; k < R; k += BLK) lacc[k] = 0ull;
    __syncthreads();

    const int per = (((E + nslice - 1) / nslice) + 7) & ~7;
    const int beg = s * per;
    const int end = min(beg + per, E);
    const int end8 = beg + (max(end - beg, 0) & ~7);

    for (int i = beg + threadIdx.x * 8; i < end8; i += BLK * 8) {
        // 4 independent 16B index loads issued together
        const int4 da = *(const int4*)&edst[i];
        const int4 db = *(const int4*)&edst[i + 4];
        const int4 sa = *(const int4*)&esrc[i];
        const int4 sb = *(const int4*)&esrc[i + 4];
        const unsigned dl0 = (unsigned)(da.x - pBeg);
        const unsigned dl1 = (unsigned)(da.y - pBeg);
        const unsigned dl2 = (unsigned)(da.z - pBeg);
        const unsigned dl3 = (unsigned)(da.w - pBeg);
        const unsigned dl4 = (unsigned)(db.x - pBeg);
        const unsigned dl5 = (unsigned)(db.y - pBeg);
        const unsigned dl6 = (unsigned)(db.z - pBeg);
        const unsigned dl7 = (unsigned)(db.w - pBeg);
        const bool h0 = dl0 < (unsigned)R, h1 = dl1 < (unsigned)R;
        const bool h2 = dl2 < (unsigned)R, h3 = dl3 < (unsigned)R;
        const bool h4 = dl4 < (unsigned)R, h5 = dl5 < (unsigned)R;
        const bool h6 = dl6 < (unsigned)R, h7 = dl7 < (unsigned)R;
        // 8 masked 8B gathers from the L2-resident pu table, all in
        // flight before the first atomic: one drain per 4096 visits
        unsigned long long v0 = 0, v1 = 0, v2 = 0, v3 = 0;
        unsigned long long v4 = 0, v5 = 0, v6 = 0, v7 = 0;
        if (h0) v0 = pu[sa.x];
        if (h1) v1 = pu[sa.y];
        if (h2) v2 = pu[sa.z];
        if (h3) v3 = pu[sa.w];
        if (h4) v4 = pu[sb.x];
        if (h5) v5 = pu[sb.y];
        if (h6) v6 = pu[sb.z];
        if (h7) v7 = pu[sb.w];
        if (h0) atomicAdd(&lacc[dl0], v0);
        if (h1) atomicAdd(&lacc[dl1], v1);
        if (h2) atomicAdd(&lacc[dl2], v2);
        if (h3) atomicAdd(&lacc[dl3], v3);
        if (h4) atomicAdd(&lacc[dl4], v4);
        if (h5) atomicAdd(&lacc[dl5], v5);
        if (h6) atomicAdd(&lacc[dl6], v6);
        if (h7) atomicAdd(&lacc[dl7], v7);
    }
    for (int i = end8 + threadIdx.x; i < end; i += BLK) {
        const unsigned dl = (unsigned)(edst[i] - pBeg);
        if (dl < (unsigned)R) atomicAdd(&lacc[dl], pu[esrc[i]]);
    }

    __syncthreads();
    unsigned long long* dst = partials + (size_t)blockIdx.x * R;
    for (int k = threadIdx.x; k < R; k += BLK) dst[k] = lacc[k];
}

// ---------------- reduce partials (raw u64 sum) + epilogue ----------------
__global__ __launch_bounds__(256) void reduce_kernel(
        const float* __restrict__ theta,
        const unsigned long long* __restrict__ partials,
        float* __restrict__ out, int N, int R, int nslice) {
    const int n = blockIdx.x * blockDim.x + threadIdx.x;
    if (n >= N) return;
    const int p = n / R;
    const int j = n - p * R;
    const unsigned long long* base = partials + (size_t)p * nslice * R + j;
    unsigned long long t = 0ull;
    #pragma unroll 8
    for (int s = 0; s < nslice; ++s) t += base[(size_t)s * R];
    const long long k  = (long long)(t >> 52);
    const long long cf = (long long)(t & 0x3FFFFFFull);
    const long long sf = (long long)((t >> 26) & 0x3FFFFFFull);
    const float C  = (float)(cf - k * 32768) * (1.0f / 32768.0f);
    const float Sv = (float)(sf - k * 32768) * (1.0f / 32768.0f);
    float sn, cs;
    __sincosf(theta[n], &sn, &cs);
    const float nrm = fmaxf(sqrtf(C * C + Sv * Sv), EPS);
    out[3 * n + 0] = cs;
    out[3 * n + 1] = sn;
    out[3 * n + 2] = (cs * Sv - sn * C) / nrm;
}

// ---------------- R8 fallback: global native atomics ----------------
__global__ __launch_bounds__(256) void prep_acc_kernel(float2* __restrict__ acc, int N) {
    int i = blockIdx.x * blockDim.x + threadIdx.x;
    if (i < N) acc[i] = make_float2(0.0f, 0.0f);
}

__global__ __launch_bounds__(256) void edge_scatter_sincos_kernel(
        const int* __restrict__ esrc,
        const int* __restrict__ edst,
        const float* __restrict__ x,
        float2* __restrict__ acc, int E) {
    const int i = (blockIdx.x * 256 + threadIdx.x) * 4;
    float* accf = (float*)acc;
    for (int k = i; k < min(i + 4, E); ++k) {
        float sn, cs;
        __sincosf(x[esrc[k]], &sn, &cs);
        const int d = edst[k];
        unsafeAtomicAdd(&accf[2 * d],     cs);
        unsafeAtomicAdd(&accf[2 * d + 1], sn);
    }
}

__global__ __launch_bounds__(256) void node_kernel(
        const float* __restrict__ theta,
        const float2* __restrict__ acc,
        float* __restrict__ out, int N) {
    int n = blockIdx.x * blockDim.x + threadIdx.x;
    if (n >= N) return;
    float sn, cs;
    __sincosf(theta[n], &sn, &cs);
    const float2 a = acc[n];
    const float nrm = fmaxf(sqrtf(a.x * a.x + a.y * a.y), EPS);
    out[3 * n + 0] = cs;
    out[3 * n + 1] = sn;
    out[3 * n + 2] = (cs * a.y - sn * a.x) / nrm;
}

extern "C" void kernel_launch(void* const* d_in, const int* in_sizes, int n_in,
                              void* d_out, int out_size, void* d_ws, size_t ws_size,
                              hipStream_t stream) {
    const float* x     = (const float*)d_in[0];
    const float* theta = (const float*)d_in[1];
    const int*   esrc  = (const int*)d_in[2];
    const int*   edst  = (const int*)d_in[3];
    float*       out   = (float*)d_out;

    const int N = in_sizes[0];
    const int E = in_sizes[2];
    const size_t pu_bytes = (size_t)N * sizeof(unsigned long long);

    // ---------- main path: NPART=16, static 50KB, 8 edges/lane ----------
    {
        const int R = (N + NPART - 1) / NPART;
        if (R <= RMAX) {
            for (int nslice : {48, 24, 8}) {
                const size_t part_bytes =
                    (size_t)NPART * nslice * R * sizeof(unsigned long long);
                if (ws_size >= part_bytes + pu_bytes) {
                    unsigned long long* partials = (unsigned long long*)d_ws;
                    unsigned long long* pu =
                        (unsigned long long*)((char*)d_ws + part_bytes);
                    prep_pack_kernel<<<(N + 255) / 256, 256, 0, stream>>>(x, pu, N);
                    scatter_kernel<<<NPART * nslice, BLK, 0, stream>>>(
                        pu, esrc, edst, partials, E, R, nslice);
                    reduce_kernel<<<(N + 255) / 256, 256, 0, stream>>>(
                        theta, partials, out, N, R, nslice);
                    return;
                }
            }
        }
    }

    // ---------- R8 fallback: global native atomics ----------
    float2* acc = (float2*)d_ws;   // 800KB
    prep_acc_kernel<<<(N + 255) / 256, 256, 0, stream>>>(acc, N);
    edge_scatter_sincos_kernel<<<(E + 1023) / 1024, 256, 0, stream>>>(esrc, edst, x, acc, E);
    node_kernel<<<(N + 255) / 256, 256, 0, stream>>>(theta, acc, out, N);
}

// Round 15
// 172.919 us; speedup vs baseline: 1.3940x; 1.0427x over previous
//
#include <hip/hip_runtime.h>
#include <math.h>

// N=100000 nodes, E=6400000 edges, avg degree 64.
// out[n] = [cos(th_n), sin(th_n), w_n],  w_n = S_y / max(||S||, eps),
//   S_x = cos(th)*C + sin(th)*S,  S_y = cos(th)*S - sin(th)*C,
//   C_n = sum_{e:dst=n} cos(x[src_e]),  S_n = sum_{e:dst=n} sin(x[src_e]).
//
// Model (R1-R14): global fp atomics write through to HBM (634us, R1/R8).
// LDS-partition rescan is LATENCY-bound: ~0.6-0.7 cyc/edge-visit/CU,
// insensitive to payload VALU (R11) and atomic width (R10), sensitive to
// per-wave MLP (R14: 8 edges/lane, 112->98us) and resident waves (R13:
// 8 waves/CU -> 168us REGRESSION). >64KB dynamic LDS breaks graph replay
// (R12). Static 50KB is the residency sweet spot.
// R15: same NPART=16/50KB/8-edges-per-lane structure, but BLK=1024 with
// nslice=32 -> grid 512 = 2 blocks/CU x 16 waves = 32 waves/CU (the HW
// cap, up from 24). Pure latency-hiding play: predicted scatter ~75us.
// Fixed-point u64: addend=(1<<52)|(sin+32768)<<26|(cos+32768), scale
// 2^15; per-node-per-slice degree << 4096 => no cross-field carry.

#define EPS 1e-12f
#define NPART 16
#define RMAX 6250        // u64[6250] = 50KB static LDS; 2 blk/CU @ BLK=1024
#define BLK 1024

static __device__ __forceinline__ unsigned long long pack_cs(float xv) {
    float sn, cs;
    __sincosf(xv, &sn, &cs);
    const int ci = __float2int_rn(cs * 32768.0f);   // [-32768, 32768]
    const int si = __float2int_rn(sn * 32768.0f);
    return (1ull << 52)
         | ((unsigned long long)(unsigned)(si + 32768) << 26)
         | (unsigned long long)(unsigned)(ci + 32768);
}

// ---------------- prep: packed-addend table ----------------
__global__ __launch_bounds__(256) void prep_pack_kernel(
        const float* __restrict__ x,
        unsigned long long* __restrict__ pu, int N) {
    int i = blockIdx.x * blockDim.x + threadIdx.x;
    if (i < N) pu[i] = pack_cs(x[i]);
}

// ---------------- scatter: 1024 thr, 50KB static, 8 edges/lane ----------
__global__ __launch_bounds__(BLK, 2) void scatter_kernel(
        const unsigned long long* __restrict__ pu,
        const int* __restrict__ esrc,
        const int* __restrict__ edst,
        unsigned long long* __restrict__ partials,   // [NPART*nslice][R]
        int E, int R, int nslice) {
    __shared__ unsigned long long lacc[RMAX];
    const int p = blockIdx.x / nslice;
    const int s = blockIdx.x % nslice;   // nslice%8==0 -> XCD = blk%8 = s%8
    const int pBeg = p * R;

    for (int k = threadIdx.x; k < R; k += BLK) lacc[k] = 0ull;
    __syncthreads();

    const int per = (((E + nslice - 1) / nslice) + 7) & ~7;
    const int beg = s * per;
    const int end = min(beg + per, E);
    const int end8 = beg + (max(end - beg, 0) & ~7);

    for (int i = beg + threadIdx.x * 8; i < end8; i += BLK * 8) {
        // 4 independent 16B index loads issued together
        const int4 da = *(const int4*)&edst[i];
        const int4 db = *(const int4*)&edst[i + 4];
        const int4 sa = *(const int4*)&esrc[i];
        const int4 sb = *(const int4*)&esrc[i + 4];
        const unsigned dl0 = (unsigned)(da.x - pBeg);
        const unsigned dl1 = (unsigned)(da.y - pBeg);
        const unsigned dl2 = (unsigned)(da.z - pBeg);
        const unsigned dl3 = (unsigned)(da.w - pBeg);
        const unsigned dl4 = (unsigned)(db.x - pBeg);
        const unsigned dl5 = (unsigned)(db.y - pBeg);
        const unsigned dl6 = (unsigned)(db.z - pBeg);
        const unsigned dl7 = (unsigned)(db.w - pBeg);
        const bool h0 = dl0 < (unsigned)R, h1 = dl1 < (unsigned)R;
        const bool h2 = dl2 < (unsigned)R, h3 = dl3 < (unsigned)R;
        const bool h4 = dl4 < (unsigned)R, h5 = dl5 < (unsigned)R;
        const bool h6 = dl6 < (unsigned)R, h7 = dl7 < (unsigned)R;
        // 8 masked 8B gathers from the L2-resident pu table, all in
        // flight before the first atomic
        unsigned long long v0 = 0, v1 = 0, v2 = 0, v3 = 0;
        unsigned long long v4 = 0, v5 = 0, v6 = 0, v7 = 0;
        if (h0) v0 = pu[sa.x];
        if (h1) v1 = pu[sa.y];
        if (h2) v2 = pu[sa.z];
        if (h3) v3 = pu[sa.w];
        if (h4) v4 = pu[sb.x];
        if (h5) v5 = pu[sb.y];
        if (h6) v6 = pu[sb.z];
        if (h7) v7 = pu[sb.w];
        if (h0) atomicAdd(&lacc[dl0], v0);
        if (h1) atomicAdd(&lacc[dl1], v1);
        if (h2) atomicAdd(&lacc[dl2], v2);
        if (h3) atomicAdd(&lacc[dl3], v3);
        if (h4) atomicAdd(&lacc[dl4], v4);
        if (h5) atomicAdd(&lacc[dl5], v5);
        if (h6) atomicAdd(&lacc[dl6], v6);
        if (h7) atomicAdd(&lacc[dl7], v7);
    }
    for (int i = end8 + threadIdx.x; i < end; i += BLK) {
        const unsigned dl = (unsigned)(edst[i] - pBeg);
        if (dl < (unsigned)R) atomicAdd(&lacc[dl], pu[esrc[i]]);
    }

    __syncthreads();
    unsigned long long* dst = partials + (size_t)blockIdx.x * R;
    for (int k = threadIdx.x; k < R; k += BLK) dst[k] = lacc[k];
}

// ---------------- reduce partials (raw u64 sum) + epilogue ----------------
__global__ __launch_bounds__(256) void reduce_kernel(
        const float* __restrict__ theta,
        const unsigned long long* __restrict__ partials,
        float* __restrict__ out, int N, int R, int nslice) {
    const int n = blockIdx.x * blockDim.x + threadIdx.x;
    if (n >= N) return;
    const int p = n / R;
    const int j = n - p * R;
    const unsigned long long* base = partials + (size_t)p * nslice * R + j;
    unsigned long long t = 0ull;
    #pragma unroll 8
    for (int s = 0; s < nslice; ++s) t += base[(size_t)s * R];
    const long long k  = (long long)(t >> 52);
    const long long cf = (long long)(t & 0x3FFFFFFull);
    const long long sf = (long long)((t >> 26) & 0x3FFFFFFull);
    const float C  = (float)(cf - k * 32768) * (1.0f / 32768.0f);
    const float Sv = (float)(sf - k * 32768) * (1.0f / 32768.0f);
    float sn, cs;
    __sincosf(theta[n], &sn, &cs);
    const float nrm = fmaxf(sqrtf(C * C + Sv * Sv), EPS);
    out[3 * n + 0] = cs;
    out[3 * n + 1] = sn;
    out[3 * n + 2] = (cs * Sv - sn * C) / nrm;
}

// ---------------- R8 fallback: global native atomics ----------------
__global__ __launch_bounds__(256) void prep_acc_kernel(float2* __restrict__ acc, int N) {
    int i = blockIdx.x * blockDim.x + threadIdx.x;
    if (i < N) acc[i] = make_float2(0.0f, 0.0f);
}

__global__ __launch_bounds__(256) void edge_scatter_sincos_kernel(
        const int* __restrict__ esrc,
        const int* __restrict__ edst,
        const float* __restrict__ x,
        float2* __restrict__ acc, int E) {
    const int i = (blockIdx.x * 256 + threadIdx.x) * 4;
    float* accf = (float*)acc;
    for (int k = i; k < min(i + 4, E); ++k) {
        float sn, cs;
        __sincosf(x[esrc[k]], &sn, &cs);
        const int d = edst[k];
        unsafeAtomicAdd(&accf[2 * d],     cs);
        unsafeAtomicAdd(&accf[2 * d + 1], sn);
    }
}

__global__ __launch_bounds__(256) void node_kernel(
        const float* __restrict__ theta,
        const float2* __restrict__ acc,
        float* __restrict__ out, int N) {
    int n = blockIdx.x * blockDim.x + threadIdx.x;
    if (n >= N) return;
    float sn, cs;
    __sincosf(theta[n], &sn, &cs);
    const float2 a = acc[n];
    const float nrm = fmaxf(sqrtf(a.x * a.x + a.y * a.y), EPS);
    out[3 * n + 0] = cs;
    out[3 * n + 1] = sn;
    out[3 * n + 2] = (cs * a.y - sn * a.x) / nrm;
}

extern "C" void kernel_launch(void* const* d_in, const int* in_sizes, int n_in,
                              void* d_out, int out_size, void* d_ws, size_t ws_size,
                              hipStream_t stream) {
    const float* x     = (const float*)d_in[0];
    const float* theta = (const float*)d_in[1];
    const int*   esrc  = (const int*)d_in[2];
    const int*   edst  = (const int*)d_in[3];
    float*       out   = (float*)d_out;

    const int N = in_sizes[0];
    const int E = in_sizes[2];
    const size_t pu_bytes = (size_t)N * sizeof(unsigned long long);

    // ---------- main path: NPART=16, static 50KB, BLK=1024, 32 waves/CU ----
    {
        const int R = (N + NPART - 1) / NPART;
        if (R <= RMAX) {
            for (int nslice : {32, 16, 8}) {
                const size_t part_bytes =
                    (size_t)NPART * nslice * R * sizeof(unsigned long long);
                if (ws_size >= part_bytes + pu_bytes) {
                    unsigned long long* partials = (unsigned long long*)d_ws;
                    unsigned long long* pu =
                        (unsigned long long*)((char*)d_ws + part_bytes);
                    prep_pack_kernel<<<(N + 255) / 256, 256, 0, stream>>>(x, pu, N);
                    scatter_kernel<<<NPART * nslice, BLK, 0, stream>>>(
                        pu, esrc, edst, partials, E, R, nslice);
                    reduce_kernel<<<(N + 255) / 256, 256, 0, stream>>>(
                        theta, partials, out, N, R, nslice);
                    return;
                }
            }
        }
    }

    // ---------- R8 fallback: global native atomics ----------
    float2* acc = (float2*)d_ws;   // 800KB
    prep_acc_kernel<<<(N + 255) / 256, 256, 0, stream>>>(acc, N);
    edge_scatter_sincos_kernel<<<(E + 1023) / 1024, 256, 0, stream>>>(esrc, edst, x, acc, E);
    node_kernel<<<(N + 255) / 256, 256, 0, stream>>>(theta, acc, out, N);
}